// Round 2
// baseline (579.880 us; speedup 1.0000x reference)
//
#include <hip/hip_runtime.h>

typedef unsigned int uint;

#define D_IN 128
#define D_H  128
#define D_OUT 16

// ---- CSR construction ------------------------------------------------------

__global__ void k_count(const int* __restrict__ dst, int E, int N, int* __restrict__ deg) {
    int e = blockIdx.x * blockDim.x + threadIdx.x;
    if (e < E) {
        int d = dst[e];
        if ((unsigned)d < (unsigned)N) atomicAdd(&deg[d], 1);
    }
}

// per-1024-chunk exclusive scan; block total -> bsum
__global__ void k_scan1(const int* __restrict__ deg, int N, int* __restrict__ rowptr,
                        int* __restrict__ bsum) {
    __shared__ int sdata[256];
    int t = threadIdx.x;
    int base = blockIdx.x * 1024;
    int idx = base + t * 4;
    int v[4];
    int s = 0;
#pragma unroll
    for (int j = 0; j < 4; j++) {
        int i = idx + j;
        v[j] = (i < N) ? deg[i] : 0;
        s += v[j];
    }
    sdata[t] = s;
    __syncthreads();
    for (int off = 1; off < 256; off <<= 1) {
        int x = (t >= off) ? sdata[t - off] : 0;
        __syncthreads();
        sdata[t] += x;
        __syncthreads();
    }
    int run = sdata[t] - s;  // exclusive prefix of this thread's 4-group
    if (t == 255) bsum[blockIdx.x] = sdata[255];
#pragma unroll
    for (int j = 0; j < 4; j++) {
        int i = idx + j;
        if (i < N) rowptr[i] = run;
        run += v[j];
    }
}

// single-block exclusive scan of block sums (nb <= 1024)
__global__ void k_scan2(int* __restrict__ bsum, int nb) {
    __shared__ int sdata[1024];
    int t = threadIdx.x;
    int v = (t < nb) ? bsum[t] : 0;
    sdata[t] = v;
    __syncthreads();
    for (int off = 1; off < 1024; off <<= 1) {
        int x = (t >= off) ? sdata[t - off] : 0;
        __syncthreads();
        sdata[t] += x;
        __syncthreads();
    }
    if (t < nb) bsum[t] = sdata[t] - v;
}

__global__ void k_scan3(const int* __restrict__ bsum, int N, int* __restrict__ rowptr) {
    int i = blockIdx.x * blockDim.x + threadIdx.x;
    if (i < N) rowptr[i] += bsum[i >> 10];
}

__global__ void k_fill(const int* __restrict__ src, const int* __restrict__ dst, int E, int N,
                       int* __restrict__ cursor, int* __restrict__ ssrc) {
    int e = blockIdx.x * blockDim.x + threadIdx.x;
    if (e < E) {
        int d = dst[e];
        int s = src[e];
        if ((unsigned)d >= (unsigned)N) return;
        if (s < 0) s = 0;
        if (s >= N) s = N - 1;
        int p = atomicAdd(&cursor[d], 1);
        ssrc[p] = s;
    }
}

__global__ void k_dinv(const int* __restrict__ deg, int N, float* __restrict__ dinv) {
    int i = blockIdx.x * blockDim.x + threadIdx.x;
    if (i < N) dinv[i] = rsqrtf((float)deg[i] + 1.0f);  // +1 = self-loop
}

// ---- GEMM1: hs = dinv[i] * (x @ W1) ----------------------------------------
// block 256; 128 rows/block; thread t: rows (t>>3)*4.. (4 of them), features (t&7)*16..+15
// W chunk in LDS as [slab fg][kk][16] + 4-float pad per slab -> each fg's reads hit a
// distinct bank quad (banks 4*fg + j), conflict-free b128s.

__global__ __launch_bounds__(256) void k_gemm1(const float* __restrict__ x,
                                               const float* __restrict__ W1,
                                               const float* __restrict__ dinv, int N,
                                               float* __restrict__ hs) {
    __shared__ float Wl[8 * 516];    // 16.5 KB
    __shared__ float xl[32 * 132];   // 16.9 KB  [kk][row(128)+pad4]
    int t = threadIdx.x;
    int fg = t & 7, rs = t >> 3;
    int row0 = blockIdx.x * 128;
    float acc[4][16];
#pragma unroll
    for (int a = 0; a < 4; a++)
#pragma unroll
        for (int b = 0; b < 16; b++) acc[a][b] = 0.f;

    for (int cb = 0; cb < 4; cb++) {  // K chunks of 32
        __syncthreads();
        for (int i = t; i < 4096; i += 256) {
            int kk = i >> 7, f = i & 127;
            Wl[(f >> 4) * 516 + kk * 16 + (f & 15)] = W1[(size_t)(cb * 32 + kk) * 128 + f];
        }
        for (int i = t; i < 4096; i += 256) {
            int r = i >> 5, kk = i & 31;
            int gr = row0 + r;
            xl[kk * 132 + r] = (gr < N) ? x[(size_t)gr * 128 + cb * 32 + kk] : 0.f;
        }
        __syncthreads();
        const float* wb = &Wl[fg * 516];
        const float* xb = &xl[rs * 4];
#pragma unroll 4
        for (int kk = 0; kk < 32; kk++) {
            float4 xv = *(const float4*)&xb[kk * 132];
            float4 w0 = *(const float4*)&wb[kk * 16];
            float4 w1 = *(const float4*)&wb[kk * 16 + 4];
            float4 w2 = *(const float4*)&wb[kk * 16 + 8];
            float4 w3 = *(const float4*)&wb[kk * 16 + 12];
            float xr[4] = {xv.x, xv.y, xv.z, xv.w};
            float wf[16] = {w0.x, w0.y, w0.z, w0.w, w1.x, w1.y, w1.z, w1.w,
                            w2.x, w2.y, w2.z, w2.w, w3.x, w3.y, w3.z, w3.w};
#pragma unroll
            for (int a = 0; a < 4; a++)
#pragma unroll
                for (int b = 0; b < 16; b++) acc[a][b] = fmaf(xr[a], wf[b], acc[a][b]);
        }
    }
#pragma unroll
    for (int a = 0; a < 4; a++) {
        int gr = row0 + rs * 4 + a;
        if (gr < N) {
            float sc = dinv[gr];
#pragma unroll
            for (int q = 0; q < 4; q++) {
                float4 o = make_float4(acc[a][q * 4] * sc, acc[a][q * 4 + 1] * sc,
                                       acc[a][q * 4 + 2] * sc, acc[a][q * 4 + 3] * sc);
                *(float4*)&hs[(size_t)gr * 128 + fg * 16 + q * 4] = o;
            }
        }
    }
}

// ---- AGG1: rh = relu(dinv[d]*(sum_{s in in(d)} hs[s] + hs[d]) + b1) --------
// one wave per node; lane = float2 (128 features = 64 float2)

__global__ __launch_bounds__(256) void k_agg1(const float2* __restrict__ hs,
                                              const int* __restrict__ rowptr,
                                              const int* __restrict__ deg,
                                              const int* __restrict__ ssrc,
                                              const float* __restrict__ dinv,
                                              const float2* __restrict__ b1, int N,
                                              float2* __restrict__ rh) {
    int w = threadIdx.x >> 6, lane = threadIdx.x & 63;
    int d = blockIdx.x * 4 + w;
    if (d >= N) return;
    int start = rowptr[d], cnt = deg[d];
    float2 sv = hs[(size_t)d * 64 + lane];  // self-loop
    float a0 = sv.x, a1 = sv.y;
    int j = 0;
    for (; j + 4 <= cnt; j += 4) {
        int i0 = ssrc[start + j], i1 = ssrc[start + j + 1];
        int i2 = ssrc[start + j + 2], i3 = ssrc[start + j + 3];
        float2 v0 = hs[(size_t)i0 * 64 + lane];
        float2 v1 = hs[(size_t)i1 * 64 + lane];
        float2 v2 = hs[(size_t)i2 * 64 + lane];
        float2 v3 = hs[(size_t)i3 * 64 + lane];
        a0 += v0.x + v1.x + v2.x + v3.x;
        a1 += v0.y + v1.y + v2.y + v3.y;
    }
    for (; j < cnt; j++) {
        float2 v = hs[(size_t)ssrc[start + j] * 64 + lane];
        a0 += v.x;
        a1 += v.y;
    }
    float sc = dinv[d];
    float2 bb = b1[lane];
    rh[(size_t)d * 64 + lane] =
        make_float2(fmaxf(fmaf(a0, sc, bb.x), 0.f), fmaxf(fmaf(a1, sc, bb.y), 0.f));
}

// ---- GEMM2: h2s = dinv[i] * (rh @ W2) --------------------------------------
// one row per thread; W2 in LDS, broadcast float4 reads

__global__ __launch_bounds__(256) void k_gemm2(const float* __restrict__ rh,
                                               const float* __restrict__ W2,
                                               const float* __restrict__ dinv, int N,
                                               float* __restrict__ h2s) {
    __shared__ float Wl[D_H * D_OUT];  // 8 KB
    int t = threadIdx.x;
    for (int i = t; i < D_H * D_OUT; i += 256) Wl[i] = W2[i];
    __syncthreads();
    int r = blockIdx.x * 256 + t;
    if (r >= N) return;
    const float* xrow = &rh[(size_t)r * 128];
    float acc[16];
#pragma unroll
    for (int b = 0; b < 16; b++) acc[b] = 0.f;
    for (int k4 = 0; k4 < 32; k4++) {
        float4 xv = *(const float4*)&xrow[k4 * 4];
        float xr[4] = {xv.x, xv.y, xv.z, xv.w};
#pragma unroll
        for (int kj = 0; kj < 4; kj++) {
            const float* wr = &Wl[(k4 * 4 + kj) * 16];
            float4 wa = *(const float4*)&wr[0];
            float4 wb2 = *(const float4*)&wr[4];
            float4 wc = *(const float4*)&wr[8];
            float4 wd = *(const float4*)&wr[12];
            float wf[16] = {wa.x, wa.y, wa.z, wa.w, wb2.x, wb2.y, wb2.z, wb2.w,
                            wc.x, wc.y, wc.z, wc.w, wd.x, wd.y, wd.z, wd.w};
#pragma unroll
            for (int b = 0; b < 16; b++) acc[b] = fmaf(xr[kj], wf[b], acc[b]);
        }
    }
    float sc = dinv[r];
#pragma unroll
    for (int q = 0; q < 4; q++) {
        float4 o = make_float4(acc[q * 4] * sc, acc[q * 4 + 1] * sc, acc[q * 4 + 2] * sc,
                               acc[q * 4 + 3] * sc);
        *(float4*)&h2s[(size_t)r * 16 + q * 4] = o;
    }
}

// ---- AGG2: out = dinv[d]*(sum h2s[s] + h2s[d]) + b2 ------------------------
// one wave per node: lane = (edge slot e4 = lane>>4, feature f = lane&15)

__global__ __launch_bounds__(256) void k_agg2(const float* __restrict__ h2s,
                                              const int* __restrict__ rowptr,
                                              const int* __restrict__ deg,
                                              const int* __restrict__ ssrc,
                                              const float* __restrict__ dinv,
                                              const float* __restrict__ b2, int N,
                                              float* __restrict__ out) {
    int w = threadIdx.x >> 6, lane = threadIdx.x & 63;
    int d = blockIdx.x * 4 + w;
    if (d >= N) return;
    int e4 = lane >> 4, f = lane & 15;
    int start = rowptr[d], cnt = deg[d];
    float acc = (e4 == 0) ? h2s[(size_t)d * 16 + f] : 0.f;  // self-loop
    for (int j = e4; j < cnt; j += 4) {
        int s = ssrc[start + j];
        acc += h2s[(size_t)s * 16 + f];
    }
    acc += __shfl_xor(acc, 32);
    acc += __shfl_xor(acc, 16);
    if (e4 == 0) out[(size_t)d * 16 + f] = fmaf(acc, dinv[d], b2[f]);
}

// ---- launch ----------------------------------------------------------------

extern "C" void kernel_launch(void* const* d_in, const int* in_sizes, int n_in,
                              void* d_out, int out_size, void* d_ws, size_t ws_size,
                              hipStream_t stream) {
    const float* x  = (const float*)d_in[0];
    const int*   ei = (const int*)d_in[1];
    const float* W1 = (const float*)d_in[2];
    const float* b1 = (const float*)d_in[3];
    const float* W2 = (const float*)d_in[4];
    const float* b2 = (const float*)d_in[5];
    int N = in_sizes[0] / D_IN;
    int E = in_sizes[1] / 2;
    const int* src = ei;
    const int* dst = ei + E;

    char* ws = (char*)d_ws;
    size_t off = 0;
    auto alloc = [&](size_t bytes) -> char* {
        char* p = ws + off;
        off = (off + bytes + 255) & ~(size_t)255;
        return p;
    };
    int*   deg    = (int*)alloc((size_t)N * 4);
    int*   rowptr = (int*)alloc((size_t)N * 4);
    int*   cursor = (int*)alloc((size_t)N * 4);
    int*   bsum   = (int*)alloc(4096);
    int*   ssrc   = (int*)alloc((size_t)E * 4);
    float* dinv   = (float*)alloc((size_t)N * 4);
    float* hs     = (float*)alloc((size_t)N * D_H * 4);
    float* rh     = (float*)alloc((size_t)N * D_H * 4);
    float* h2s    = hs;  // hs dead after k_agg1; reuse

    hipMemsetAsync(deg, 0, (size_t)N * 4, stream);
    int gE = (E + 255) / 256;
    k_count<<<gE, 256, 0, stream>>>(dst, E, N, deg);
    int nb = (N + 1023) / 1024;
    k_scan1<<<nb, 256, 0, stream>>>(deg, N, rowptr, bsum);
    k_scan2<<<1, 1024, 0, stream>>>(bsum, nb);
    k_scan3<<<(N + 255) / 256, 256, 0, stream>>>(bsum, N, rowptr);
    hipMemcpyAsync(cursor, rowptr, (size_t)N * 4, hipMemcpyDeviceToDevice, stream);
    k_fill<<<gE, 256, 0, stream>>>(src, dst, E, N, cursor, ssrc);
    k_dinv<<<(N + 255) / 256, 256, 0, stream>>>(deg, N, dinv);
    k_gemm1<<<(N + 127) / 128, 256, 0, stream>>>(x, W1, dinv, N, hs);
    k_agg1<<<(N + 3) / 4, 256, 0, stream>>>((const float2*)hs, rowptr, deg, ssrc, dinv,
                                            (const float2*)b1, N, (float2*)rh);
    k_gemm2<<<(N + 255) / 256, 256, 0, stream>>>(rh, W2, dinv, N, h2s);
    k_agg2<<<(N + 3) / 4, 256, 0, stream>>>(h2s, rowptr, deg, ssrc, dinv, b2, N,
                                            (float*)d_out);
}

// Round 3
// 545.039 us; speedup vs baseline: 1.0639x; 1.0639x over previous
//
#include <hip/hip_runtime.h>

typedef unsigned int uint;

#define D_IN 128
#define D_H  128
#define D_OUT 16
#define BSH 4                 // 16 nodes per bucket
#define BNODES (1 << BSH)

// ---- bucket-binned CSR construction ---------------------------------------

__global__ void k_bhist(const int* __restrict__ dst, int E, int N, int* __restrict__ bcount) {
    int e = blockIdx.x * blockDim.x + threadIdx.x;
    if (e < E) {
        int d = dst[e];
        if ((unsigned)d < (unsigned)N) atomicAdd(&bcount[d >> BSH], 1);
    }
}

// single-block exclusive scan over nbk (<= 8192) bucket counts
__global__ __launch_bounds__(1024) void k_bscan(const int* __restrict__ bcount, int nbk,
                                                int* __restrict__ bbase,
                                                int* __restrict__ bcursor) {
    __shared__ int sdata[1024];
    int t = threadIdx.x;
    int per = (nbk + 1023) / 1024;  // 7 for N=100K
    int base = t * per;
    int v[12];
    int s = 0;
    for (int j = 0; j < per; j++) {
        int i = base + j;
        v[j] = (i < nbk) ? bcount[i] : 0;
        s += v[j];
    }
    sdata[t] = s;
    __syncthreads();
    for (int off = 1; off < 1024; off <<= 1) {
        int x = (t >= off) ? sdata[t - off] : 0;
        __syncthreads();
        sdata[t] += x;
        __syncthreads();
    }
    int run = sdata[t] - s;
    for (int j = 0; j < per; j++) {
        int i = base + j;
        if (i < nbk) { bbase[i] = run; bcursor[i] = run; }
        run += v[j];
    }
}

// scatter packed (dst_local<<17 | src) into bucket-contiguous regions
__global__ void k_bfill(const int* __restrict__ src, const int* __restrict__ dst, int E, int N,
                        int* __restrict__ bcursor, uint* __restrict__ binned) {
    int e = blockIdx.x * blockDim.x + threadIdx.x;
    if (e < E) {
        int d = dst[e];
        if ((unsigned)d >= (unsigned)N) return;
        int s = src[e];
        if (s < 0) s = 0;
        if (s >= N) s = N - 1;
        int p = atomicAdd(&bcursor[d >> BSH], 1);
        binned[p] = ((uint)(d & (BNODES - 1)) << 17) | (uint)s;
    }
}

// one block per bucket: local count -> local scan -> deg/rowptr + final ssrc
__global__ __launch_bounds__(256) void k_bcsr(const uint* __restrict__ binned,
                                              const int* __restrict__ bbase,
                                              const int* __restrict__ bcount, int N,
                                              int* __restrict__ deg, int* __restrict__ rowptr,
                                              int* __restrict__ ssrc) {
    __shared__ int lcnt[BNODES], lbase[BNODES], lcur[BNODES];
    int b = blockIdx.x;
    int t = threadIdx.x;
    int start = bbase[b], cnt = bcount[b];
    if (t < BNODES) lcnt[t] = 0;
    __syncthreads();
    for (int j = t; j < cnt; j += 256) atomicAdd(&lcnt[binned[start + j] >> 17], 1);
    __syncthreads();
    if (t == 0) {
        int run = start;
        for (int i = 0; i < BNODES; i++) {
            lbase[i] = run;
            lcur[i] = run;
            run += lcnt[i];
        }
    }
    __syncthreads();
    if (t < BNODES) {
        int node = b * BNODES + t;
        if (node < N) {
            deg[node] = lcnt[t];
            rowptr[node] = lbase[t];
        }
    }
    for (int j = t; j < cnt; j += 256) {
        uint p = binned[start + j];
        int pos = atomicAdd(&lcur[p >> 17], 1);
        ssrc[pos] = (int)(p & 0x1FFFFu);
    }
}

__global__ void k_dinv(const int* __restrict__ deg, int N, float* __restrict__ dinv) {
    int i = blockIdx.x * blockDim.x + threadIdx.x;
    if (i < N) dinv[i] = rsqrtf((float)deg[i] + 1.0f);  // +1 = self-loop
}

// ---- GEMM1: hs = dinv[i] * (x @ W1) ----------------------------------------
// block 256; 128 rows/block; thread t: rows (t>>3)*4.. (4 of them), features (t&7)*16..+15

__global__ __launch_bounds__(256) void k_gemm1(const float* __restrict__ x,
                                               const float* __restrict__ W1,
                                               const float* __restrict__ dinv, int N,
                                               float* __restrict__ hs) {
    __shared__ float Wl[8 * 516];    // 16.5 KB
    __shared__ float xl[32 * 132];   // 16.9 KB  [kk][row(128)+pad4]
    int t = threadIdx.x;
    int fg = t & 7, rs = t >> 3;
    int row0 = blockIdx.x * 128;
    float acc[4][16];
#pragma unroll
    for (int a = 0; a < 4; a++)
#pragma unroll
        for (int b = 0; b < 16; b++) acc[a][b] = 0.f;

    for (int cb = 0; cb < 4; cb++) {  // K chunks of 32
        __syncthreads();
        for (int i = t; i < 4096; i += 256) {
            int kk = i >> 7, f = i & 127;
            Wl[(f >> 4) * 516 + kk * 16 + (f & 15)] = W1[(size_t)(cb * 32 + kk) * 128 + f];
        }
        for (int i = t; i < 4096; i += 256) {
            int r = i >> 5, kk = i & 31;
            int gr = row0 + r;
            xl[kk * 132 + r] = (gr < N) ? x[(size_t)gr * 128 + cb * 32 + kk] : 0.f;
        }
        __syncthreads();
        const float* wb = &Wl[fg * 516];
        const float* xb = &xl[rs * 4];
#pragma unroll 4
        for (int kk = 0; kk < 32; kk++) {
            float4 xv = *(const float4*)&xb[kk * 132];
            float4 w0 = *(const float4*)&wb[kk * 16];
            float4 w1 = *(const float4*)&wb[kk * 16 + 4];
            float4 w2 = *(const float4*)&wb[kk * 16 + 8];
            float4 w3 = *(const float4*)&wb[kk * 16 + 12];
            float xr[4] = {xv.x, xv.y, xv.z, xv.w};
            float wf[16] = {w0.x, w0.y, w0.z, w0.w, w1.x, w1.y, w1.z, w1.w,
                            w2.x, w2.y, w2.z, w2.w, w3.x, w3.y, w3.z, w3.w};
#pragma unroll
            for (int a = 0; a < 4; a++)
#pragma unroll
                for (int b = 0; b < 16; b++) acc[a][b] = fmaf(xr[a], wf[b], acc[a][b]);
        }
    }
#pragma unroll
    for (int a = 0; a < 4; a++) {
        int gr = row0 + rs * 4 + a;
        if (gr < N) {
            float sc = dinv[gr];
#pragma unroll
            for (int q = 0; q < 4; q++) {
                float4 o = make_float4(acc[a][q * 4] * sc, acc[a][q * 4 + 1] * sc,
                                       acc[a][q * 4 + 2] * sc, acc[a][q * 4 + 3] * sc);
                *(float4*)&hs[(size_t)gr * 128 + fg * 16 + q * 4] = o;
            }
        }
    }
}

// ---- AGG1: rh = relu(dinv[d]*(sum_{s in in(d)} hs[s] + hs[d]) + b1) --------
// one wave per node; lane = float2 (128 features = 64 float2)

__global__ __launch_bounds__(256) void k_agg1(const float2* __restrict__ hs,
                                              const int* __restrict__ rowptr,
                                              const int* __restrict__ deg,
                                              const int* __restrict__ ssrc,
                                              const float* __restrict__ dinv,
                                              const float2* __restrict__ b1, int N,
                                              float2* __restrict__ rh) {
    int w = threadIdx.x >> 6, lane = threadIdx.x & 63;
    int d = blockIdx.x * 4 + w;
    if (d >= N) return;
    int start = rowptr[d], cnt = deg[d];
    float2 sv = hs[(size_t)d * 64 + lane];  // self-loop
    float a0 = sv.x, a1 = sv.y;
    int j = 0;
    for (; j + 4 <= cnt; j += 4) {
        int i0 = ssrc[start + j], i1 = ssrc[start + j + 1];
        int i2 = ssrc[start + j + 2], i3 = ssrc[start + j + 3];
        float2 v0 = hs[(size_t)i0 * 64 + lane];
        float2 v1 = hs[(size_t)i1 * 64 + lane];
        float2 v2 = hs[(size_t)i2 * 64 + lane];
        float2 v3 = hs[(size_t)i3 * 64 + lane];
        a0 += v0.x + v1.x + v2.x + v3.x;
        a1 += v0.y + v1.y + v2.y + v3.y;
    }
    for (; j < cnt; j++) {
        float2 v = hs[(size_t)ssrc[start + j] * 64 + lane];
        a0 += v.x;
        a1 += v.y;
    }
    float sc = dinv[d];
    float2 bb = b1[lane];
    rh[(size_t)d * 64 + lane] =
        make_float2(fmaxf(fmaf(a0, sc, bb.x), 0.f), fmaxf(fmaf(a1, sc, bb.y), 0.f));
}

// ---- GEMM2: h2s = dinv[i] * (rh @ W2) --------------------------------------

__global__ __launch_bounds__(256) void k_gemm2(const float* __restrict__ rh,
                                               const float* __restrict__ W2,
                                               const float* __restrict__ dinv, int N,
                                               float* __restrict__ h2s) {
    __shared__ float Wl[D_H * D_OUT];  // 8 KB
    int t = threadIdx.x;
    for (int i = t; i < D_H * D_OUT; i += 256) Wl[i] = W2[i];
    __syncthreads();
    int r = blockIdx.x * 256 + t;
    if (r >= N) return;
    const float* xrow = &rh[(size_t)r * 128];
    float acc[16];
#pragma unroll
    for (int b = 0; b < 16; b++) acc[b] = 0.f;
    for (int k4 = 0; k4 < 32; k4++) {
        float4 xv = *(const float4*)&xrow[k4 * 4];
        float xr[4] = {xv.x, xv.y, xv.z, xv.w};
#pragma unroll
        for (int kj = 0; kj < 4; kj++) {
            const float* wr = &Wl[(k4 * 4 + kj) * 16];
            float4 wa = *(const float4*)&wr[0];
            float4 wb2 = *(const float4*)&wr[4];
            float4 wc = *(const float4*)&wr[8];
            float4 wd = *(const float4*)&wr[12];
            float wf[16] = {wa.x, wa.y, wa.z, wa.w, wb2.x, wb2.y, wb2.z, wb2.w,
                            wc.x, wc.y, wc.z, wc.w, wd.x, wd.y, wd.z, wd.w};
#pragma unroll
            for (int b = 0; b < 16; b++) acc[b] = fmaf(xr[kj], wf[b], acc[b]);
        }
    }
    float sc = dinv[r];
#pragma unroll
    for (int q = 0; q < 4; q++) {
        float4 o = make_float4(acc[q * 4] * sc, acc[q * 4 + 1] * sc, acc[q * 4 + 2] * sc,
                               acc[q * 4 + 3] * sc);
        *(float4*)&h2s[(size_t)r * 16 + q * 4] = o;
    }
}

// ---- AGG2: out = dinv[d]*(sum h2s[s] + h2s[d]) + b2 ------------------------

__global__ __launch_bounds__(256) void k_agg2(const float* __restrict__ h2s,
                                              const int* __restrict__ rowptr,
                                              const int* __restrict__ deg,
                                              const int* __restrict__ ssrc,
                                              const float* __restrict__ dinv,
                                              const float* __restrict__ b2, int N,
                                              float* __restrict__ out) {
    int w = threadIdx.x >> 6, lane = threadIdx.x & 63;
    int d = blockIdx.x * 4 + w;
    if (d >= N) return;
    int e4 = lane >> 4, f = lane & 15;
    int start = rowptr[d], cnt = deg[d];
    float acc = (e4 == 0) ? h2s[(size_t)d * 16 + f] : 0.f;  // self-loop
    for (int j = e4; j < cnt; j += 4) {
        int s = ssrc[start + j];
        acc += h2s[(size_t)s * 16 + f];
    }
    acc += __shfl_xor(acc, 32);
    acc += __shfl_xor(acc, 16);
    if (e4 == 0) out[(size_t)d * 16 + f] = fmaf(acc, dinv[d], b2[f]);
}

// ---- launch ----------------------------------------------------------------

extern "C" void kernel_launch(void* const* d_in, const int* in_sizes, int n_in,
                              void* d_out, int out_size, void* d_ws, size_t ws_size,
                              hipStream_t stream) {
    const float* x  = (const float*)d_in[0];
    const int*   ei = (const int*)d_in[1];
    const float* W1 = (const float*)d_in[2];
    const float* b1 = (const float*)d_in[3];
    const float* W2 = (const float*)d_in[4];
    const float* b2 = (const float*)d_in[5];
    int N = in_sizes[0] / D_IN;
    int E = in_sizes[1] / 2;
    const int* src = ei;
    const int* dst = ei + E;
    int nbk = (N + BNODES - 1) / BNODES;

    char* ws = (char*)d_ws;
    size_t off = 0;
    auto alloc = [&](size_t bytes) -> char* {
        char* p = ws + off;
        off = (off + bytes + 255) & ~(size_t)255;
        return p;
    };
    int*   bcount  = (int*)alloc((size_t)nbk * 4);
    int*   bbase   = (int*)alloc((size_t)nbk * 4);
    int*   bcursor = (int*)alloc((size_t)nbk * 4);
    uint*  binned  = (uint*)alloc((size_t)E * 4);
    int*   deg     = (int*)alloc((size_t)N * 4);
    int*   rowptr  = (int*)alloc((size_t)N * 4);
    int*   ssrc    = (int*)alloc((size_t)E * 4);
    float* dinv    = (float*)alloc((size_t)N * 4);
    float* hs      = (float*)alloc((size_t)N * D_H * 4);
    float* rh      = (float*)alloc((size_t)N * D_H * 4);
    float* h2s     = hs;  // hs dead after k_agg1; reuse

    hipMemsetAsync(bcount, 0, (size_t)nbk * 4, stream);
    int gE = (E + 255) / 256;
    k_bhist<<<gE, 256, 0, stream>>>(dst, E, N, bcount);
    k_bscan<<<1, 1024, 0, stream>>>(bcount, nbk, bbase, bcursor);
    k_bfill<<<gE, 256, 0, stream>>>(src, dst, E, N, bcursor, binned);
    k_bcsr<<<nbk, 256, 0, stream>>>(binned, bbase, bcount, N, deg, rowptr, ssrc);
    k_dinv<<<(N + 255) / 256, 256, 0, stream>>>(deg, N, dinv);
    k_gemm1<<<(N + 127) / 128, 256, 0, stream>>>(x, W1, dinv, N, hs);
    k_agg1<<<(N + 3) / 4, 256, 0, stream>>>((const float2*)hs, rowptr, deg, ssrc, dinv,
                                            (const float2*)b1, N, (float2*)rh);
    k_gemm2<<<(N + 255) / 256, 256, 0, stream>>>(rh, W2, dinv, N, h2s);
    k_agg2<<<(N + 3) / 4, 256, 0, stream>>>(h2s, rowptr, deg, ssrc, dinv, b2, N,
                                            (float*)d_out);
}